// Round 2
// baseline (2364.114 us; speedup 1.0000x reference)
//
#include <hip/hip_runtime.h>
#include <hip/hip_fp16.h>

#define NW 16384
#define TMAX 16
#define VOCAB 128
#define EDIM 128
#define HDIM 256
#define G4 1024

typedef _Float16 f16;
typedef _Float16 f16x8 __attribute__((ext_vector_type(8)));
typedef float f32x4 __attribute__((ext_vector_type(4)));

// ---------------- kernel 1: Gih[dir][v][g] = emb[v] . Wih[g] + b[g]  (f16) ----
__global__ void gih_kernel(const float* __restrict__ emb,
                           const float* __restrict__ WihF, const float* __restrict__ bF,
                           const float* __restrict__ WihB, const float* __restrict__ bB,
                           f16* __restrict__ gih) {
    int dir = blockIdx.x >> 7;      // 256 blocks: 2 dirs x 128 vocab
    int v   = blockIdx.x & 127;
    const float* Wih = dir ? WihB : WihF;
    const float* bb  = dir ? bB  : bF;
    __shared__ float ev[EDIM];
    int t = threadIdx.x;            // 256 threads
    if (t < EDIM) ev[t] = emb[v * EDIM + t];
    __syncthreads();
#pragma unroll
    for (int q = 0; q < 4; ++q) {
        int g = q * 256 + t;
        const float4* w4 = reinterpret_cast<const float4*>(Wih + (size_t)g * EDIM);
        float s = bb[g];
#pragma unroll
        for (int e = 0; e < EDIM / 4; ++e) {
            float4 w = w4[e];
            s += w.x * ev[e*4] + w.y * ev[e*4+1] + w.z * ev[e*4+2] + w.w * ev[e*4+3];
        }
        gih[((size_t)dir * VOCAB + v) * G4 + g] = (f16)s;
    }
}

// ---------------- kernel 2: pack Whh (f32 [1024][256]) -> f16 B-frag layout ---
// layout: bp[dir][gt(64)][kt(8)][lane(64)][8]   lane = kr*16 + (g&15), k = kt*32 + kr*8 + e
__global__ void whh_pack_kernel(const float* __restrict__ WhhF,
                                const float* __restrict__ WhhB,
                                f16* __restrict__ bp) {
    int idx = blockIdx.x * 256 + threadIdx.x;   // grid 2048 -> 524288 = 2*1024*256
    int dir = idx >> 18;
    int rem = idx & 262143;
    int g = rem >> 8;
    int k = rem & 255;
    const float* W = dir ? WhhB : WhhF;
    float val = W[(size_t)g * HDIM + k];
    int gt = g >> 4, col = g & 15;
    int kt = k >> 5, kr = (k >> 3) & 3, e = k & 7;
    int lane = kr * 16 + col;
    size_t off = ((((size_t)dir * 64 + gt) * 8 + kt) * 64 + lane) * 8 + e;
    bp[off] = (f16)val;
}

// ---------------- kernel 3: the LSTM ----------------------------------------
// grid 512 (dir = b&1, tile = b>>1), block 256 = 4 waves.
// block owns 64 seqs; wave w owns H-column tiles j in [4w, 4w+4).
// h: LDS f16 [64][256], byte = (row*512 + col*2) ^ ((row&7)<<4)
// c: f32 VGPRs, lane-owned per C/D layout (row = (lane>>4)*4+r, col = lane&15)
__global__ __launch_bounds__(256, 1)
void lstm_kernel(const int* __restrict__ char_ids, const int* __restrict__ lengths,
                 const f16* __restrict__ gih, const f16* __restrict__ bp,
                 float* __restrict__ out) {
    int dir  = blockIdx.x & 1;
    int tile = blockIdx.x >> 1;
    int seq0 = tile * 64;

    __shared__ __align__(16) unsigned char h_bytes[64 * 512];  // 32 KB
    __shared__ int cid_s[64 * 16];
    __shared__ int len_s[64];

    int tid  = threadIdx.x;
    int lane = tid & 63;
    int wid  = tid >> 6;
    int l15  = lane & 15;
    int l4   = lane >> 4;

    // init h = 0
    {
        float4 z = {0.f, 0.f, 0.f, 0.f};
#pragma unroll
        for (int i = 0; i < 8; ++i)
            *reinterpret_cast<float4*>(&h_bytes[(i * 256 + tid) * 16]) = z;
    }
#pragma unroll
    for (int i = 0; i < 4; ++i) {
        int idx = i * 256 + tid;
        cid_s[idx] = char_ids[(size_t)seq0 * 16 + idx];
    }
    if (tid < 64) len_s[tid] = lengths[seq0 + tid];
    __syncthreads();

    float c_reg[4][4][4];   // [m][j][r]
#pragma unroll
    for (int m = 0; m < 4; ++m)
#pragma unroll
        for (int j = 0; j < 4; ++j)
#pragma unroll
            for (int r = 0; r < 4; ++r) c_reg[m][j][r] = 0.f;

    const f16* bp_d  = bp  + (size_t)dir * 64 * 8 * 64 * 8;
    const f16* gih_d = gih + (size_t)dir * VOCAB * G4;

#pragma unroll 1
    for (int s = 0; s < TMAX; ++s) {
        int tt = dir ? (TMAX - 1 - s) : s;

        // A-fragments: all 4 M-tiles, all K, held in regs (128 VGPR)
        f16x8 a[4][8];
#pragma unroll
        for (int m = 0; m < 4; ++m) {
            int row = m * 16 + l15;
            int sw  = (row & 7) << 4;
#pragma unroll
            for (int kt = 0; kt < 8; ++kt) {
                int off = (row * 512 + (kt * 32 + l4 * 8) * 2) ^ sw;
                a[m][kt] = *reinterpret_cast<const f16x8*>(&h_bytes[off]);
            }
        }
        __syncthreads();   // everyone has read old h; writes may begin

#pragma unroll
        for (int j = 0; j < 4; ++j) {
            int jj = wid * 4 + j;
            f32x4 acc[4][4];  // [gate][m]
#pragma unroll
            for (int gg = 0; gg < 4; ++gg)
#pragma unroll
                for (int m = 0; m < 4; ++m) acc[gg][m] = (f32x4){0.f, 0.f, 0.f, 0.f};

#pragma unroll
            for (int gate = 0; gate < 4; ++gate) {
                int gt = gate * 16 + jj;
                const f16x8* bsrc =
                    reinterpret_cast<const f16x8*>(bp_d + (size_t)gt * 8 * 64 * 8) + lane;
#pragma unroll
                for (int kt = 0; kt < 8; ++kt) {
                    f16x8 bfrag = bsrc[kt * 64];
#pragma unroll
                    for (int m = 0; m < 4; ++m)
                        acc[gate][m] = __builtin_amdgcn_mfma_f32_16x16x32_f16(
                            a[m][kt], bfrag, acc[gate][m], 0, 0, 0);
                }
            }

            // epilogue: gather Gih, activations, masked state update
#pragma unroll
            for (int m = 0; m < 4; ++m) {
#pragma unroll
                for (int r = 0; r < 4; ++r) {
                    int row = m * 16 + l4 * 4 + r;
                    int len = len_s[row];
                    if (tt < len) {
                        int cid = cid_s[row * 16 + tt];
                        const f16* grow = gih_d + (size_t)cid * G4 + jj * 16 + l15;
                        float gi = acc[0][m][r] + (float)grow[0];
                        float gf = acc[1][m][r] + (float)grow[256];
                        float gg = acc[2][m][r] + (float)grow[512];
                        float go = acc[3][m][r] + (float)grow[768];
                        float i_ = 1.f / (1.f + __expf(-gi));
                        float f_ = 1.f / (1.f + __expf(-gf));
                        float zg = __expf(2.f * gg);
                        float g_ = 1.f - 2.f / (zg + 1.f);
                        float o_ = 1.f / (1.f + __expf(-go));
                        float cn = f_ * c_reg[m][j][r] + i_ * g_;
                        c_reg[m][j][r] = cn;
                        float zt = __expf(2.f * cn);
                        float th = 1.f - 2.f / (zt + 1.f);
                        float hn = o_ * th;
                        int col = jj * 16 + l15;
                        int off = (row * 512 + col * 2) ^ ((row & 7) << 4);
                        *reinterpret_cast<f16*>(&h_bytes[off]) = (f16)hn;
                    }
                }
            }
        }
        __syncthreads();   // h writes visible for next step
    }

    // write out: out[seq][dir*256 + col], f32
    for (int i = 0; i < 64; ++i) {
        int idx  = i * 256 + tid;
        int srow = idx >> 8;
        int col  = idx & 255;
        int off  = (srow * 512 + col * 2) ^ ((srow & 7) << 4);
        f16 hv   = *reinterpret_cast<const f16*>(&h_bytes[off]);
        out[(size_t)(seq0 + srow) * 512 + dir * 256 + col] = (float)hv;
    }
}

// ---------------------------------------------------------------------------
extern "C" void kernel_launch(void* const* d_in, const int* in_sizes, int n_in,
                              void* d_out, int out_size, void* d_ws, size_t ws_size,
                              hipStream_t stream) {
    (void)in_sizes; (void)n_in; (void)out_size; (void)ws_size;
    const int*   char_ids = (const int*)d_in[0];
    const int*   lengths  = (const int*)d_in[1];
    const float* emb      = (const float*)d_in[2];
    const float* Wih_f    = (const float*)d_in[3];
    const float* Whh_f    = (const float*)d_in[4];
    const float* b_f      = (const float*)d_in[5];
    const float* Wih_b    = (const float*)d_in[6];
    const float* Whh_b    = (const float*)d_in[7];
    const float* b_b      = (const float*)d_in[8];
    float* out = (float*)d_out;

    f16* gih = (f16*)d_ws;                    // 2*128*1024 f16 = 512 KB
    f16* bp  = gih + 2 * VOCAB * G4;          // 2*64*8*64*8 f16 = 1 MB

    gih_kernel<<<256, 256, 0, stream>>>(emb, Wih_f, b_f, Wih_b, b_b, gih);
    whh_pack_kernel<<<2048, 256, 0, stream>>>(Whh_f, Whh_b, bp);
    lstm_kernel<<<512, 256, 0, stream>>>(char_ids, lengths, gih, bp, out);
}

// Round 3
// 1164.021 us; speedup vs baseline: 2.0310x; 2.0310x over previous
//
#include <hip/hip_runtime.h>
#include <hip/hip_fp16.h>

#define VOCAB 128
#define TMAX 16

typedef _Float16 f16;
typedef _Float16 f16x4 __attribute__((ext_vector_type(4)));
typedef _Float16 f16x8 __attribute__((ext_vector_type(8)));
typedef float f32x4 __attribute__((ext_vector_type(4)));

// ---- kernel 1: gih2[dir][v][col(256)][gate(4)] = emb[v].Wih[gate*256+col] + b
__global__ void gih_kernel(const float* __restrict__ emb,
                           const float* __restrict__ WihF, const float* __restrict__ bF,
                           const float* __restrict__ WihB, const float* __restrict__ bB,
                           f16* __restrict__ gih) {
    int dir = blockIdx.x >> 7;      // 256 blocks: 2 dirs x 128 vocab
    int v   = blockIdx.x & 127;
    const float* Wih = dir ? WihB : WihF;
    const float* bb  = dir ? bB : bF;
    __shared__ float ev[128];
    int t = threadIdx.x;            // 256 threads
    if (t < 128) ev[t] = emb[v*128 + t];
    __syncthreads();
#pragma unroll
    for (int qq = 0; qq < 4; ++qq) {
        int g = qq*256 + t;         // gate=qq, col=t
        const float4* w4 = (const float4*)(Wih + (size_t)g * 128);
        float s = bb[g];
#pragma unroll
        for (int e = 0; e < 32; ++e) {
            float4 wv = w4[e];
            s += wv.x*ev[e*4] + wv.y*ev[e*4+1] + wv.z*ev[e*4+2] + wv.w*ev[e*4+3];
        }
        gih[((size_t)(dir*VOCAB + v)*256 + t)*4 + qq] = (f16)s;
    }
}

// ---- kernel 2: pack Whh f32[1024][256] -> f16 bp2[dir][jj(16)][gate(4)][kt(8)][lane(64)][e(8)]
// B-fragment (16x16x32): col = lane&15, k = kt*32 + (lane>>4)*8 + e
__global__ void whh_pack_kernel(const float* __restrict__ WhhF,
                                const float* __restrict__ WhhB,
                                f16* __restrict__ bp) {
    int idx = blockIdx.x * 256 + threadIdx.x;   // grid 2048 -> 524288 = 2*1024*256
    int dir = idx >> 18;
    int rem = idx & 262143;
    int g = rem >> 8;       // 0..1023
    int k = rem & 255;
    const float* W = dir ? WhhB : WhhF;
    float val = W[(size_t)g * 256 + k];
    int gate = g >> 8;
    int jj   = (g >> 4) & 15;
    int c15  = g & 15;
    int kt = k >> 5, kr = (k >> 3) & 3, e = k & 7;
    int lane = kr*16 + c15;
    size_t off = ((((size_t)(dir*16 + jj)*4 + gate)*8 + kt)*64 + lane)*8 + e;
    bp[off] = (f16)val;
}

// ---- kernel 3: LSTM. 256 blocks (1/CU) x 512 threads (8 waves).
// Wave w owns seqs [grp*128 + w*16, +16): h is wave-private LDS (XOR-swizzled).
// Whh streams via triple-buffered 16KB LDS chunks (reg-staged, 1-chunk lead).
__global__ __launch_bounds__(512, 2)
void lstm_kernel(const int* __restrict__ char_ids, const int* __restrict__ lengths,
                 const f16* __restrict__ gih, const f16* __restrict__ bp2,
                 float* __restrict__ out) {
    const int dir  = blockIdx.x & 1;
    const int grp  = blockIdx.x >> 1;
    const int seq0 = grp * 128;

    __shared__ __align__(16) unsigned char lds[123392];
    unsigned char* h_lds = lds;                 // 64 KB: 128 rows x 512B
    unsigned char* bbuf  = lds + 65536;         // 3 x 16 KB chunk buffers
    int* cid_s = (int*)(lds + 114688);          // 2048 ints
    int* len_s = (int*)(lds + 122880);          // 128 ints

    const int tid  = threadIdx.x;
    const int lane = tid & 63;
    const int w    = tid >> 6;
    const int l15  = lane & 15;
    const int q    = lane >> 4;

    // prologue: cids/lens to LDS, zero h
#pragma unroll
    for (int i = 0; i < 4; ++i)
        cid_s[i*512 + tid] = char_ids[(size_t)seq0*16 + i*512 + tid];
    if (tid < 128) len_s[tid] = lengths[seq0 + tid];
    {
        float4 z = {0.f, 0.f, 0.f, 0.f};
#pragma unroll
        for (int i = 0; i < 8; ++i)
            *(float4*)(h_lds + w*8192 + (i*64 + lane)*16) = z;
    }
    __syncthreads();

    const f16* bp_d  = bp2 + (size_t)dir * 262144;
    const f16* gih_d = gih + (size_t)dir * (VOCAB * 1024);

    int rowg[4], len_c[4];
#pragma unroll
    for (int r = 0; r < 4; ++r) { rowg[r] = w*16 + q*4 + r; len_c[r] = len_s[rowg[r]]; }

    int tt = dir ? 15 : 0;
    int cid_c[4];
#pragma unroll
    for (int r = 0; r < 4; ++r) cid_c[r] = cid_s[rowg[r]*16 + tt];

    const int u0 = w*128 + lane;   // 16B staging units (2 per thread per chunk)
    const int u1 = u0 + 64;

    // stage chunks 0,1 -> buf0,buf1 ; prefetch gih pair 0
    f16x4 grow[2][4];
#pragma unroll
    for (int r = 0; r < 4; ++r)
        grow[0][r] = *(const f16x4*)(gih_d + (size_t)cid_c[r]*1024 + l15*4);
    {
        f16x8 s00 = *(const f16x8*)(bp_d + 0*8192 + u0*8);
        f16x8 s01 = *(const f16x8*)(bp_d + 0*8192 + u1*8);
        f16x8 s10 = *(const f16x8*)(bp_d + 1*8192 + u0*8);
        f16x8 s11 = *(const f16x8*)(bp_d + 1*8192 + u1*8);
        *(f16x8*)(bbuf + 0     + u0*16) = s00;
        *(f16x8*)(bbuf + 0     + u1*16) = s01;
        *(f16x8*)(bbuf + 16384 + u0*16) = s10;
        *(f16x8*)(bbuf + 16384 + u1*16) = s11;
    }
    __syncthreads();

    float c_st[16][4];
#pragma unroll
    for (int p = 0; p < 16; ++p)
#pragma unroll
        for (int r = 0; r < 4; ++r) c_st[p][r] = 0.f;

    int roff = 0, woff = 32768;
    const int hbase = w * 8192;
    const int aswz  = (l15 & 7) << 4;

#pragma unroll 1
    for (int s = 0; s < TMAX; ++s) {
        // A fragments: own 16 rows x K=256 (row = l15, k = kt*32 + q*8 + e)
        f16x8 a[8];
#pragma unroll
        for (int kt = 0; kt < 8; ++kt) {
            int off = (l15*512 + (kt*32 + q*8)*2) ^ aswz;
            a[kt] = *(const f16x8*)(h_lds + hbase + off);
        }

        int ttn = dir ? (tt > 0 ? tt - 1 : 0) : (tt < 15 ? tt + 1 : 15);
        int cid_n[4];
        f32x4 acc0, acc1, acc2, acc3;

#pragma unroll
        for (int p = 0; p < 16; ++p) {
            const int pp = p & 1;
            // ========== even chunk: gates i,f of tile jj=p ==========
            f16x8 sA, sB;
            {
                const int cs = (p*2 + 2) & 31;      // compile-time per unrolled p
                sA = *(const f16x8*)(bp_d + cs*8192 + u0*8);
                sB = *(const f16x8*)(bp_d + cs*8192 + u1*8);
            }
            if (p == 15) {
#pragma unroll
                for (int r = 0; r < 4; ++r) cid_n[r] = cid_s[rowg[r]*16 + ttn];
                grow[pp^1][0] = *(const f16x4*)(gih_d + (size_t)cid_n[0]*1024 + l15*4);
                grow[pp^1][1] = *(const f16x4*)(gih_d + (size_t)cid_n[1]*1024 + l15*4);
            } else {
                grow[pp^1][0] = *(const f16x4*)(gih_d + (size_t)cid_c[0]*1024 + ((p+1)*16 + l15)*4);
                grow[pp^1][1] = *(const f16x4*)(gih_d + (size_t)cid_c[1]*1024 + ((p+1)*16 + l15)*4);
            }
            acc0 = (f32x4){0.f,0.f,0.f,0.f}; acc1 = (f32x4){0.f,0.f,0.f,0.f};
#pragma unroll
            for (int kt = 0; kt < 8; ++kt) {
                f16x8 b0 = *(const f16x8*)(bbuf + roff + ((0*8 + kt)*64 + lane)*16);
                acc0 = __builtin_amdgcn_mfma_f32_16x16x32_f16(a[kt], b0, acc0, 0, 0, 0);
            }
#pragma unroll
            for (int kt = 0; kt < 8; ++kt) {
                f16x8 b1 = *(const f16x8*)(bbuf + roff + ((1*8 + kt)*64 + lane)*16);
                acc1 = __builtin_amdgcn_mfma_f32_16x16x32_f16(a[kt], b1, acc1, 0, 0, 0);
            }
            *(f16x8*)(bbuf + woff + u0*16) = sA;    // commit chunk C+2
            *(f16x8*)(bbuf + woff + u1*16) = sB;
            roff = (roff == 32768) ? 0 : roff + 16384;
            woff = (woff == 32768) ? 0 : woff + 16384;
            __syncthreads();

            // ========== odd chunk: gates g,o of tile jj=p ==========
            {
                const int cs = (p*2 + 3) & 31;
                sA = *(const f16x8*)(bp_d + cs*8192 + u0*8);
                sB = *(const f16x8*)(bp_d + cs*8192 + u1*8);
            }
            if (p == 15) {
                grow[pp^1][2] = *(const f16x4*)(gih_d + (size_t)cid_n[2]*1024 + l15*4);
                grow[pp^1][3] = *(const f16x4*)(gih_d + (size_t)cid_n[3]*1024 + l15*4);
            } else {
                grow[pp^1][2] = *(const f16x4*)(gih_d + (size_t)cid_c[2]*1024 + ((p+1)*16 + l15)*4);
                grow[pp^1][3] = *(const f16x4*)(gih_d + (size_t)cid_c[3]*1024 + ((p+1)*16 + l15)*4);
            }
            acc2 = (f32x4){0.f,0.f,0.f,0.f}; acc3 = (f32x4){0.f,0.f,0.f,0.f};
#pragma unroll
            for (int kt = 0; kt < 8; ++kt) {
                f16x8 b2 = *(const f16x8*)(bbuf + roff + ((0*8 + kt)*64 + lane)*16);
                acc2 = __builtin_amdgcn_mfma_f32_16x16x32_f16(a[kt], b2, acc2, 0, 0, 0);
            }
#pragma unroll
            for (int kt = 0; kt < 8; ++kt) {
                f16x8 b3 = *(const f16x8*)(bbuf + roff + ((1*8 + kt)*64 + lane)*16);
                acc3 = __builtin_amdgcn_mfma_f32_16x16x32_f16(a[kt], b3, acc3, 0, 0, 0);
            }

            // epilogue for tile jj=p (lane owns row q*4+r, col p*16+l15)
#pragma unroll
            for (int r = 0; r < 4; ++r) {
                f16x4 g4 = grow[pp][r];
                float gi = acc0[r] + (float)g4[0];
                float gf = acc1[r] + (float)g4[1];
                float gg = acc2[r] + (float)g4[2];
                float go = acc3[r] + (float)g4[3];
                float i_ = 1.f / (1.f + __expf(-gi));
                float f_ = 1.f / (1.f + __expf(-gf));
                float zg = __expf(2.f * gg);
                float g_ = 1.f - 2.f / (zg + 1.f);
                float o_ = 1.f / (1.f + __expf(-go));
                float cn = f_ * c_st[p][r] + i_ * g_;
                float zt = __expf(2.f * cn);
                float th = 1.f - 2.f / (zt + 1.f);
                float hn = o_ * th;
                if (tt < len_c[r]) {
                    c_st[p][r] = cn;
                    int row = q*4 + r;
                    int off = (row*512 + (p*16 + l15)*2) ^ ((row & 7) << 4);
                    *(f16*)(h_lds + hbase + off) = (f16)hn;
                }
            }

            *(f16x8*)(bbuf + woff + u0*16) = sA;    // commit chunk C+2
            *(f16x8*)(bbuf + woff + u1*16) = sB;
            roff = (roff == 32768) ? 0 : roff + 16384;
            woff = (woff == 32768) ? 0 : woff + 16384;
            __syncthreads();
        }

        tt = ttn;
#pragma unroll
        for (int r = 0; r < 4; ++r) cid_c[r] = cid_n[r];
    }

    // write out: f32 [16384][512], own rows
#pragma unroll
    for (int row = 0; row < 16; ++row) {
#pragma unroll
        for (int cc = 0; cc < 4; ++cc) {
            int col = cc*64 + lane;
            int off = (row*512 + col*2) ^ ((row & 7) << 4);
            f16 hv = *(const f16*)(h_lds + hbase + off);
            out[(size_t)(seq0 + w*16 + row)*512 + dir*256 + col] = (float)hv;
        }
    }
}

// ---------------------------------------------------------------------------
extern "C" void kernel_launch(void* const* d_in, const int* in_sizes, int n_in,
                              void* d_out, int out_size, void* d_ws, size_t ws_size,
                              hipStream_t stream) {
    (void)in_sizes; (void)n_in; (void)out_size; (void)ws_size;
    const int*   char_ids = (const int*)d_in[0];
    const int*   lengths  = (const int*)d_in[1];
    const float* emb      = (const float*)d_in[2];
    const float* Wih_f    = (const float*)d_in[3];
    const float* Whh_f    = (const float*)d_in[4];
    const float* b_f      = (const float*)d_in[5];
    const float* Wih_b    = (const float*)d_in[6];
    const float* Whh_b    = (const float*)d_in[7];
    const float* b_b      = (const float*)d_in[8];
    float* out = (float*)d_out;

    f16* gih = (f16*)d_ws;                    // 2*128*256*4 f16 = 512 KB
    f16* bp  = gih + 2 * VOCAB * 1024;        // 2*16*4*8*64*8 f16 = 1 MB

    gih_kernel<<<256, 256, 0, stream>>>(emb, Wih_f, b_f, Wih_b, b_b, gih);
    whh_pack_kernel<<<2048, 256, 0, stream>>>(Whh_f, Whh_b, bp);
    lstm_kernel<<<256, 512, 0, stream>>>(char_ids, lengths, gih, bp, out);
}